// Round 13
// baseline (556.381 us; speedup 1.0000x reference)
//
#include <hip/hip_runtime.h>
#include <hip/hip_bf16.h>

// ShiftWindowMSA fused pipeline for MI355X (gfx950).
// R13: depth-4 wave-private B buffers, prefetch distance 3 (glds issued BEFORE
// this step's ds_reads into a disjoint buffer -> no lgkm coupling), per-step
// counted vmcnt(6/3/0). 8 waves x 48-col strips (512 thr), 1 window per block.
// var0: pass0 = k (swapped), pass1 = v (unswapped); var1: q single pass.
// LDS 144 KB -> 1 block/CU (8 waves = 2/SIMD). attn unchanged.

typedef __attribute__((ext_vector_type(8))) short short8;
typedef __attribute__((ext_vector_type(4))) float floatx4;

#define MFMA16(a, b, c) __builtin_amdgcn_mfma_f32_16x16x32_bf16(a, b, c, 0, 0, 0)

__device__ __forceinline__ short f2bf(float f) {
    __hip_bfloat16 h = __float2bfloat16(f);
    return *reinterpret_cast<short*>(&h);
}

// packed fp32->bf16 RNE
__device__ __forceinline__ unsigned cvt2bf(float lo, float hi) {
    unsigned r;
    asm("v_cvt_pk_bf16_f32 %0, %1, %2" : "=v"(r) : "v"(lo), "v"(hi));
    return r;
}

__device__ __forceinline__ void glds16(const void* g, void* l) {
    __builtin_amdgcn_global_load_lds(
        (const __attribute__((address_space(1))) void*)g,
        (__attribute__((address_space(3))) void*)l, 16, 0, 0);
}

// ---------------- prep kernels ----------------

__global__ __launch_bounds__(256) void prep_wt(const float* __restrict__ Wqkv,
                                               const float* __restrict__ Wskip,
                                               short* __restrict__ Wt) {
    int tid = blockIdx.x * 256 + threadIdx.x;  // 384*144 = 55296
    if (tid >= 384 * 144) return;
    int k = tid / 144;
    int n8 = (tid % 144) * 8;
#pragma unroll
    for (int e = 0; e < 8; e++) {
        int n = n8 + e;
        float v = (n < 768) ? Wqkv[k * 768 + n]
                            : Wskip[k * 384 + (n - 768)] * 0.17677669529663687f;
        Wt[(size_t)n * 384 + k] = f2bf(v);
    }
}

__global__ __launch_bounds__(256) void prep_wtp(const float* __restrict__ Wproj,
                                                short* __restrict__ WtP) {
    int tid = blockIdx.x * 256 + threadIdx.x;  // 384*48 = 18432
    if (tid >= 384 * 48) return;
    int k = tid / 48;
    int n8 = (tid % 48) * 8;
#pragma unroll
    for (int e = 0; e < 8; e++) {
        int n = n8 + e;
        WtP[(size_t)n * 384 + k] = f2bf(Wproj[k * 384 + n]);
    }
}

__global__ __launch_bounds__(256) void prep_bias(const float* __restrict__ rpb,
                                                 float* __restrict__ bias64) {
    int tid = blockIdx.x * 256 + threadIdx.x;  // 12*64*64 = 49152
    if (tid >= 49152) return;
    int h = tid >> 12;
    int rem = tid & 4095;
    int i = rem >> 6, kk = rem & 63;
    int j = 63 - kk;
    int ridx = 15 * (i >> 3) + (i & 7) + 15 * (j >> 3) + (j & 7);
    bias64[tid] = rpb[ridx * 12 + h];
}

// ---------------- depth-4 distance-3 barrier-free 12-step K-loop ----------
// A in smemA[0..24576) chunk-swizzled (c ^ (r&7)); wave B bufs 4 x 1536 sh.
// Step kt: vmcnt(6) [tail 3/0] -> issue 3 glds for step kt+3 into buf
// (kt+3)&3 (disjoint from read buf kt&3) -> 4 A + 3 B ds_reads -> 12 MFMA.
template <bool SWP, bool FIN>
__device__ __forceinline__ void kloop12d(
    const short* __restrict__ smemA, short* __restrict__ bwb,
    const short* __restrict__ curSrc, const short* __restrict__ nxtSrc,
    const int (&bso)[3], int l15, int g4, int al7, int brd,
    floatx4 (&acc)[3][4]) {
#pragma unroll
    for (int a = 0; a < 3; a++)
#pragma unroll
        for (int b = 0; b < 4; b++)
#pragma unroll
            for (int r = 0; r < 4; r++) acc[a][b][r] = 0.f;
#pragma unroll
    for (int kt = 0; kt < 12; ++kt) {
        if (FIN && kt == 10)      asm volatile("s_waitcnt vmcnt(3)" ::: "memory");
        else if (FIN && kt == 11) asm volatile("s_waitcnt vmcnt(0)" ::: "memory");
        else                      asm volatile("s_waitcnt vmcnt(6)" ::: "memory");
        short* wb = bwb + ((kt + 3) & 3) * 1536;
        if (kt < 9) {
            int ko = (kt + 3) * 32;
#pragma unroll
            for (int j = 0; j < 3; j++) glds16(curSrc + bso[j] + ko, wb + j * 512);
        } else if (!FIN) {
            int ko = (kt - 9) * 32;
#pragma unroll
            for (int j = 0; j < 3; j++) glds16(nxtSrc + bso[j] + ko, wb + j * 512);
        }
        __builtin_amdgcn_sched_barrier(0);
        const int choff = ((kt * 4 + g4) ^ al7) * 8;
        const short* hb = bwb + (kt & 3) * 1536;
        short8 af[4], bfr[3];
#pragma unroll
        for (int b = 0; b < 4; b++)
            af[b] = *(const short8*)(smemA + (b * 16 + l15) * 384 + choff);
#pragma unroll
        for (int a = 0; a < 3; a++)
            bfr[a] = *(const short8*)(hb + (a * 16 + l15) * 32 + brd);
        if (SWP) {
#pragma unroll
            for (int a = 0; a < 3; a++)
#pragma unroll
                for (int b = 0; b < 4; b++)
                    acc[a][b] = MFMA16(bfr[a], af[b], acc[a][b]);
        } else {
#pragma unroll
            for (int a = 0; a < 3; a++)
#pragma unroll
                for (int b = 0; b < 4; b++)
                    acc[a][b] = MFMA16(af[b], bfr[a], acc[a][b]);
        }
    }
}

// ---------------- gemm_qkv ----------------
// LDS: A[64][384] 48 KB @0; 8 waves x 4 bufs x 3 KB @24576. 144 KB total.
__global__ __launch_bounds__(512, 1) void gemm_qkv(
    const float* __restrict__ xq, const float* __restrict__ xs,
    const short* __restrict__ Wt,
    const float* __restrict__ bqkv, const float* __restrict__ bskip,
    short* __restrict__ kbuf, short* __restrict__ vtbuf, short* __restrict__ qbuf) {
    __shared__ short smem[73728];

    const int win = blockIdx.x;
    const int var = blockIdx.y;          // 0: A=query -> k,v; 1: A=skip -> q
    const float* __restrict__ src = var ? xs : xq;

    const int tid = threadIdx.x, lane = tid & 63, wid = tid >> 6;
    const int l15 = lane & 15, g4 = lane >> 4;
    const int al7 = l15 & 7;
    const int brd = (g4 ^ ((l15 ^ (l15 >> 2)) & 3)) * 8;

    // ---- A gather: 64 rows x 384 fp32 (shift-window permuted) -> bf16 LDS ----
    {
        int r = tid >> 3, q8 = tid & 7;
        int b = win / 144, wr = win % 144;
        int wy = wr / 12, wx = wr % 12;
        int yy = wy * 8 + (r >> 3) + 4; if (yy >= 96) yy -= 96;
        int xx = wx * 8 + (r & 7) + 4;  if (xx >= 96) xx -= 96;
        const float* rbase = src + ((size_t)b * 9216 + yy * 96 + xx) * 384;
        short* lrow = smem + r * 384;
        int r7 = r & 7;
#pragma unroll
        for (int j = 0; j < 6; j++) {
            int c = q8 + j * 8;
            float4 f0 = *(const float4*)(rbase + c * 8);
            float4 f1 = *(const float4*)(rbase + c * 8 + 4);
            uint4 u;
            u.x = cvt2bf(f0.x, f0.y); u.y = cvt2bf(f0.z, f0.w);
            u.z = cvt2bf(f1.x, f1.y); u.w = cvt2bf(f1.z, f1.w);
            *(uint4*)(lrow + ((c ^ r7) * 8)) = u;
        }
    }

    // ---- wave-private B staging roles (3 glds of 1 KB per step, 48 rows) ----
    const int swst = ((lane >> 2) ^ (lane >> 4)) & 3;
    int bso[3];
#pragma unroll
    for (int j = 0; j < 3; j++)
        bso[j] = (j * 16 + (lane >> 2)) * 384 + (((lane & 3) ^ swst) * 8);
    short* bwb = smem + 24576 + wid * 6144;  // 4 bufs x 1536 shorts

    const short* sK = Wt + (size_t)(var ? (768 + wid * 48) : (wid * 48)) * 384;
    const short* sV = Wt + (size_t)(384 + wid * 48) * 384;

    // prologue: stage steps 0,1,2 of first pass
#pragma unroll
    for (int s = 0; s < 3; s++)
#pragma unroll
        for (int j = 0; j < 3; j++)
            glds16(sK + bso[j] + s * 32, bwb + s * 1536 + j * 512);
    __syncthreads();  // A ready; drains all counters

    floatx4 acc[3][4];
    const float scl = 0.17677669529663687f;

    if (var == 0) {
        // ---- pass0: k (swapped), chained into v ----
        kloop12d<true, false>(smem, bwb, sK, sV, bso, l15, g4, al7, brd, acc);
#pragma unroll
        for (int a = 0; a < 3; a++) {
            int nm = wid * 48 + a * 16 + g4 * 4;
            int head = nm >> 5, d0 = nm & 31;
            float4 bv = *(const float4*)(bqkv + nm);
            short* dst = kbuf + (size_t)(win * 12 + head) * 2048 + d0;
#pragma unroll
            for (int b = 0; b < 4; b++) {
                int t = b * 16 + l15;
                uint2 pk;
                pk.x = cvt2bf(acc[a][b][0] + bv.x, acc[a][b][1] + bv.y);
                pk.y = cvt2bf(acc[a][b][2] + bv.z, acc[a][b][3] + bv.w);
                *(uint2*)(dst + (size_t)t * 32) = pk;
            }
        }
        // ---- pass1: v (unswapped, final) ----
        kloop12d<false, true>(smem, bwb, sV, nullptr, bso, l15, g4, al7, brd, acc);
#pragma unroll
        for (int nj = 0; nj < 3; nj++) {
            int nm = wid * 48 + nj * 16 + l15;
            int head = nm >> 5, d = nm & 31;
            float bvs = bqkv[384 + nm];
            short* dst = vtbuf + ((size_t)(win * 12 + head) * 32 + d) * 64;
#pragma unroll
            for (int mi = 0; mi < 4; mi++) {
                int t0 = mi * 16 + g4 * 4;
                uint2 pk;
                pk.x = cvt2bf(acc[nj][mi][0] + bvs, acc[nj][mi][1] + bvs);
                pk.y = cvt2bf(acc[nj][mi][2] + bvs, acc[nj][mi][3] + bvs);
                *(uint2*)(dst + t0) = pk;
            }
        }
    } else {
        // ---- q (swapped, final; W pre-scaled, bias scaled here) ----
        kloop12d<true, true>(smem, bwb, sK, nullptr, bso, l15, g4, al7, brd, acc);
#pragma unroll
        for (int a = 0; a < 3; a++) {
            int nm = wid * 48 + a * 16 + g4 * 4;
            int head = nm >> 5, d0 = nm & 31;
            float4 bv = *(const float4*)(bskip + nm);
            short* dst = qbuf + (size_t)(win * 12 + head) * 2048 + d0;
#pragma unroll
            for (int b = 0; b < 4; b++) {
                int t = b * 16 + l15;
                uint2 pk;
                pk.x = cvt2bf(acc[a][b][0] + bv.x * scl, acc[a][b][1] + bv.y * scl);
                pk.y = cvt2bf(acc[a][b][2] + bv.z * scl, acc[a][b][3] + bv.w * scl);
                *(uint2*)(dst + (size_t)t * 32) = pk;
            }
        }
    }
}

// ---------------- attention (R7-proven) ----------------
__global__ __launch_bounds__(256) void attn_kernel(
    const short* __restrict__ kbuf, const short* __restrict__ vtbuf,
    const short* __restrict__ qbuf, const float* __restrict__ bias64,
    short* __restrict__ aout, int ntask) {
    __shared__ short lps[18432];  // 4 waves x 64 x 72
    int lane = threadIdx.x & 63, wid = threadIdx.x >> 6;
    int task = blockIdx.x * 4 + wid;
    if (task >= ntask) return;
    int win = task / 12, head = task % 12;
    int l15 = lane & 15, g4 = lane >> 4;

    const short* kb = kbuf + (size_t)task * 2048;
    const short* qb = qbuf + (size_t)task * 2048;
    const short* vb = vtbuf + (size_t)task * 2048;

    short8 kf[4], qf[4], vf[2][2];
#pragma unroll
    for (int mi = 0; mi < 4; mi++)
        kf[mi] = *(const short8*)(kb + (mi * 16 + l15) * 32 + g4 * 8);
#pragma unroll
    for (int nj = 0; nj < 4; nj++)
        qf[nj] = *(const short8*)(qb + (nj * 16 + l15) * 32 + g4 * 8);
#pragma unroll
    for (int ma = 0; ma < 2; ma++)
#pragma unroll
        for (int ks = 0; ks < 2; ks++)
            vf[ma][ks] = *(const short8*)(vb + (ma * 16 + l15) * 64 + ks * 32 + g4 * 8);

    floatx4 st[4][4];
#pragma unroll
    for (int mi = 0; mi < 4; mi++)
#pragma unroll
        for (int nj = 0; nj < 4; nj++)
#pragma unroll
            for (int r = 0; r < 4; r++) st[mi][nj][r] = 0.f;

#pragma unroll
    for (int mi = 0; mi < 4; mi++)
#pragma unroll
        for (int nj = 0; nj < 4; nj++)
            st[mi][nj] = MFMA16(kf[mi], qf[nj], st[mi][nj]);  // S^T[kk][i]

    const float* bb = bias64 + head * 4096;
#pragma unroll
    for (int nj = 0; nj < 4; nj++) {
        int i = nj * 16 + l15;
#pragma unroll
        for (int mi = 0; mi < 4; mi++) {
            floatx4 b4 = *(const floatx4*)(bb + i * 64 + mi * 16 + g4 * 4);
            st[mi][nj] += b4;
        }
    }

    int wr = win % 144;
    int wy = wr / 12, wx = wr % 12;
    if (wy == 11 || wx == 11) {
        int wy11 = (wy == 11), wx11 = (wx == 11);
        int ri[4];
#pragma unroll
        for (int nj = 0; nj < 4; nj++) {
            int t = nj * 16 + l15;
            int hh = wy11 ? (((t >> 3) >= 4) ? 2 : 1) : 0;
            int ww = wx11 ? (((t & 7) >= 4) ? 2 : 1) : 0;
            ri[nj] = hh * 3 + ww;
        }
#pragma unroll
        for (int mi = 0; mi < 4; mi++)
#pragma unroll
            for (int r = 0; r < 4; r++) {
                int t = mi * 16 + g4 * 4 + r;
                int hh = wy11 ? (((t >> 3) >= 4) ? 2 : 1) : 0;
                int ww = wx11 ? (((t & 7) >= 4) ? 2 : 1) : 0;
                int rk = hh * 3 + ww;
#pragma unroll
                for (int nj = 0; nj < 4; nj++)
                    if (rk != ri[nj]) st[mi][nj][r] -= 100.0f;
            }
    }

    float rden[4];
#pragma unroll
    for (int nj = 0; nj < 4; nj++) {
        float m = -1e30f;
#pragma unroll
        for (int mi = 0; mi < 4; mi++)
#pragma unroll
            for (int r = 0; r < 4; r++) m = fmaxf(m, st[mi][nj][r]);
        m = fmaxf(m, __shfl_xor(m, 16));
        m = fmaxf(m, __shfl_xor(m, 32));
        float s = 0.f;
#pragma unroll
        for (int mi = 0; mi < 4; mi++)
#pragma unroll
            for (int r = 0; r < 4; r++) {
                float p = __expf(st[mi][nj][r] - m);
                st[mi][nj][r] = p;
                s += p;
            }
        s += __shfl_xor(s, 16);
        s += __shfl_xor(s, 32);
        rden[nj] = 1.0f / s;
    }

    short* Lp = lps + wid * 4608;  // [64][72]
#pragma unroll
    for (int mi = 0; mi < 4; mi++)
#pragma unroll
        for (int nj = 0; nj < 4; nj++) {
            uint2 pk;
            pk.x = cvt2bf(st[mi][nj][0], st[mi][nj][1]);
            pk.y = cvt2bf(st[mi][nj][2], st[mi][nj][3]);
            *(uint2*)(Lp + (nj * 16 + l15) * 72 + mi * 16 + g4 * 4) = pk;
        }

    floatx4 o[2][4];
#pragma unroll
    for (int ma = 0; ma < 2; ma++)
#pragma unroll
        for (int nj = 0; nj < 4; nj++)
#pragma unroll
            for (int r = 0; r < 4; r++) o[ma][nj][r] = 0.f;
#pragma unroll
    for (int ks = 0; ks < 2; ks++) {
        short8 pb[4];
#pragma unroll
        for (int nj = 0; nj < 4; nj++)
            pb[nj] = *(const short8*)(Lp + (nj * 16 + l15) * 72 + ks * 32 + g4 * 8);
#pragma unroll
        for (int ma = 0; ma < 2; ma++)
#pragma unroll
            for (int nj = 0; nj < 4; nj++)
                o[ma][nj] = MFMA16(vf[ma][ks], pb[nj], o[ma][nj]);
    }

    short* ob = aout + (size_t)win * 64 * 384 + head * 32;
#pragma unroll
    for (int ma = 0; ma < 2; ma++)
#pragma unroll
        for (int nj = 0; nj < 4; nj++) {
            int i = nj * 16 + l15;
            uint2 pk;
            pk.x = cvt2bf(o[ma][nj][0] * rden[nj], o[ma][nj][1] * rden[nj]);
            pk.y = cvt2bf(o[ma][nj][2] * rden[nj], o[ma][nj][3] * rden[nj]);
            *(uint2*)(ob + (size_t)i * 384 + ma * 16 + g4 * 4) = pk;
        }
}

// ---------------- gemm_proj ----------------
__global__ __launch_bounds__(512, 1) void gemm_proj(
    const short* __restrict__ aout, const short* __restrict__ WtP,
    const float* __restrict__ bproj, float* __restrict__ out) {
    __shared__ short smem[73728];

    const int win = blockIdx.x;
    const int m0 = win * 64;
    const int tid = threadIdx.x, lane = tid & 63, wid = tid >> 6;
    const int l15 = lane & 15, g4 = lane >> 4;
    const int al7 = l15 & 7;
    const int brd = (g4 ^ ((l15 ^ (l15 >> 2)) & 3)) * 8;

    // ---- A via glds: 48 issues of 1 KB (6 per wave), pre-swizzled source ----
#pragma unroll
    for (int j = 0; j < 6; j++) {
        int i = wid * 6 + j;
        int c = i * 64 + lane;
        int row = c / 48, ch = c - row * 48;
        const short* s = aout + (size_t)(m0 + row) * 384 + ((ch ^ (row & 7)) * 8);
        glds16(s, smem + i * 512);
    }

    const int swst = ((lane >> 2) ^ (lane >> 4)) & 3;
    int bso[3];
#pragma unroll
    for (int j = 0; j < 3; j++)
        bso[j] = (j * 16 + (lane >> 2)) * 384 + (((lane & 3) ^ swst) * 8);
    short* bwb = smem + 24576 + wid * 6144;
    const short* sB = WtP + (size_t)(wid * 48) * 384;

#pragma unroll
    for (int s = 0; s < 3; s++)
#pragma unroll
        for (int j = 0; j < 3; j++)
            glds16(sB + bso[j] + s * 32, bwb + s * 1536 + j * 512);
    __syncthreads();

    floatx4 acc[3][4];
    kloop12d<true, true>(smem, bwb, sB, nullptr, bso, l15, g4, al7, brd, acc);

    const int b_img = win / 144, wrw = win % 144;
    const int wy = wrw / 12, wx = wrw % 12;
#pragma unroll
    for (int a = 0; a < 3; a++) {
        int n = wid * 48 + a * 16 + g4 * 4;
        float4 bv = *(const float4*)(bproj + n);
#pragma unroll
        for (int b = 0; b < 4; b++) {
            int t = b * 16 + l15;
            int yy = wy * 8 + (t >> 3) + 4; if (yy >= 96) yy -= 96;
            int xx = wx * 8 + (t & 7) + 4;  if (xx >= 96) xx -= 96;
            floatx4 o = acc[a][b];
            o[0] += bv.x; o[1] += bv.y; o[2] += bv.z; o[3] += bv.w;
            *(floatx4*)(&out[((size_t)b_img * 9216 + yy * 96 + xx) * 384 + n]) = o;
        }
    }
}

// ---------------- launcher ----------------
extern "C" void kernel_launch(void* const* d_in, const int* in_sizes, int n_in,
                              void* d_out, int out_size, void* d_ws, size_t ws_size,
                              hipStream_t stream) {
    const float* query = (const float*)d_in[0];
    const float* skipq = (const float*)d_in[1];
    const float* Wqkv  = (const float*)d_in[2];
    const float* bqkv  = (const float*)d_in[3];
    const float* Wskip = (const float*)d_in[4];
    const float* bskip = (const float*)d_in[5];
    const float* rpb   = (const float*)d_in[6];
    const float* Wproj = (const float*)d_in[7];
    const float* bproj = (const float*)d_in[8];
    float* out = (float*)d_out;

    int M = in_sizes[0] / 384;   // total tokens = 147456 for B=16
    int nwin = M / 64;           // 2304

    char* ws = (char*)d_ws;
    size_t off = 0;
    auto alloc = [&](size_t bytes) -> void* {
        void* p = ws + off;
        off = (off + bytes + 255) & ~(size_t)255;
        return p;
    };
    short* Wt     = (short*)alloc((size_t)1152 * 384 * 2);
    short* WtP    = (short*)alloc((size_t)384 * 384 * 2);
    float* bias64 = (float*)alloc((size_t)12 * 64 * 64 * 4);
    short* kbuf   = (short*)alloc((size_t)M * 384 * 2);
    short* vtbuf  = (short*)alloc((size_t)M * 384 * 2);
    short* qbuf   = (short*)alloc((size_t)M * 384 * 2);
    short* aout   = (short*)alloc((size_t)M * 384 * 2);
    (void)ws_size;

    hipLaunchKernelGGL(prep_wt, dim3(216), dim3(256), 0, stream, Wqkv, Wskip, Wt);
    hipLaunchKernelGGL(prep_wtp, dim3(72), dim3(256), 0, stream, Wproj, WtP);
    hipLaunchKernelGGL(prep_bias, dim3(192), dim3(256), 0, stream, rpb, bias64);
    hipLaunchKernelGGL(gemm_qkv, dim3(nwin, 2), dim3(512), 0, stream,
                       query, skipq, Wt, bqkv, bskip, kbuf, vtbuf, qbuf);
    hipLaunchKernelGGL(attn_kernel, dim3(nwin * 12 / 4), dim3(256), 0, stream,
                       kbuf, vtbuf, qbuf, bias64, aout, nwin * 12);
    hipLaunchKernelGGL(gemm_proj, dim3(nwin), dim3(512), 0, stream,
                       aout, WtP, bproj, out);
}

// Round 15
// 498.471 us; speedup vs baseline: 1.1162x; 1.1162x over previous
//
#include <hip/hip_runtime.h>
#include <hip/hip_bf16.h>

// ShiftWindowMSA fully-fused kernel for MI355X (gfx950).
// R15 = R14 + two lgkmcnt(0)/sched_barrier fences closing glds-vs-pending-
// ds_read races (qf reads vs kv-prologue glds; PV pb reads vs proj-prologue
// glds). Block = 1 window (768 thr, 12 waves, wave = head); no intermediate
// global buffers. LDS 144 KB (A 48 KB + 12 x 8 KB wave scratch).

typedef __attribute__((ext_vector_type(8))) short short8;
typedef __attribute__((ext_vector_type(4))) float floatx4;

#define MFMA16(a, b, c) __builtin_amdgcn_mfma_f32_16x16x32_bf16(a, b, c, 0, 0, 0)

__device__ __forceinline__ short f2bf(float f) {
    __hip_bfloat16 h = __float2bfloat16(f);
    return *reinterpret_cast<short*>(&h);
}

// packed fp32->bf16 RNE
__device__ __forceinline__ unsigned cvt2bf(float lo, float hi) {
    unsigned r;
    asm("v_cvt_pk_bf16_f32 %0, %1, %2" : "=v"(r) : "v"(lo), "v"(hi));
    return r;
}

__device__ __forceinline__ void glds16(const void* g, void* l) {
    __builtin_amdgcn_global_load_lds(
        (const __attribute__((address_space(1))) void*)g,
        (__attribute__((address_space(3))) void*)l, 16, 0, 0);
}

__device__ __forceinline__ void lds_fence() {
    asm volatile("s_waitcnt lgkmcnt(0)" ::: "memory");
    __builtin_amdgcn_sched_barrier(0);
}

// ---------------- prep kernels ----------------

__global__ __launch_bounds__(256) void prep_wt(const float* __restrict__ Wqkv,
                                               const float* __restrict__ Wskip,
                                               short* __restrict__ Wt) {
    int tid = blockIdx.x * 256 + threadIdx.x;  // 384*144 = 55296
    if (tid >= 384 * 144) return;
    int k = tid / 144;
    int n8 = (tid % 144) * 8;
#pragma unroll
    for (int e = 0; e < 8; e++) {
        int n = n8 + e;
        float v = (n < 768) ? Wqkv[k * 768 + n]
                            : Wskip[k * 384 + (n - 768)] * 0.17677669529663687f;
        Wt[(size_t)n * 384 + k] = f2bf(v);
    }
}

__global__ __launch_bounds__(256) void prep_wtp(const float* __restrict__ Wproj,
                                                short* __restrict__ WtP) {
    int tid = blockIdx.x * 256 + threadIdx.x;  // 384*48 = 18432
    if (tid >= 384 * 48) return;
    int k = tid / 48;
    int n8 = (tid % 48) * 8;
#pragma unroll
    for (int e = 0; e < 8; e++) {
        int n = n8 + e;
        WtP[(size_t)n * 384 + k] = f2bf(Wproj[k * 384 + n]);
    }
}

__global__ __launch_bounds__(256) void prep_bias(const float* __restrict__ rpb,
                                                 float* __restrict__ bias64) {
    int tid = blockIdx.x * 256 + threadIdx.x;  // 12*64*64 = 49152
    if (tid >= 49152) return;
    int h = tid >> 12;
    int rem = tid & 4095;
    int i = rem >> 6, kk = rem & 63;
    int j = 63 - kk;
    int ridx = 15 * (i >> 3) + (i & 7) + 15 * (j >> 3) + (j & 7);
    bias64[tid] = rpb[ridx * 12 + h];
}

// ---------------- fused per-window kernel ----------------
__global__ __launch_bounds__(768, 1) void fused_win(
    const float* __restrict__ xq, const float* __restrict__ xs,
    const short* __restrict__ Wt, const short* __restrict__ WtP,
    const float* __restrict__ bqkv, const float* __restrict__ bskip,
    const float* __restrict__ bproj, const float* __restrict__ bias64,
    float* __restrict__ out) {
    __shared__ short smem[73728];  // A/out [0,24576); wave scratch @24576+wid*4096

    const int win = blockIdx.x;
    const int tid = threadIdx.x, lane = tid & 63, wid = tid >> 6;  // wid = head
    const int l15 = lane & 15, g4 = lane >> 4;
    const int al7 = l15 & 7;
    const int brd = (g4 ^ ((l15 ^ (l15 >> 2)) & 3)) * 8;

    const int b_img = win / 144, wr = win % 144;
    const int wy = wr / 12, wx = wr % 12;

    // gather mapping: 64 rows x 12 threads (32 cols each)
    const int gr = tid / 12, gj = tid - gr * 12;
    int gyy = wy * 8 + (gr >> 3) + 4; if (gyy >= 96) gyy -= 96;
    int gxx = wx * 8 + (gr & 7) + 4;  if (gxx >= 96) gxx -= 96;
    const size_t grow = ((size_t)b_img * 9216 + gyy * 96 + gxx) * 384;
    short* lrow = smem + gr * 384;
    const int gr7 = gr & 7;

    auto gatherA = [&](const float* src) {
        const float* rb = src + grow;
#pragma unroll
        for (int cc = 0; cc < 4; cc++) {
            int c = gj * 4 + cc;
            float4 f0 = *(const float4*)(rb + c * 8);
            float4 f1 = *(const float4*)(rb + c * 8 + 4);
            uint4 u;
            u.x = cvt2bf(f0.x, f0.y); u.y = cvt2bf(f0.z, f0.w);
            u.z = cvt2bf(f1.x, f1.y); u.w = cvt2bf(f1.z, f1.w);
            *(uint4*)(lrow + ((c ^ gr7) * 8)) = u;
        }
    };

    // B strip staging (32 rows x 32 k per step = 2 glds of 1 KB)
    const int swst = ((lane >> 2) ^ (lane >> 4)) & 3;
    int bso[2];
#pragma unroll
    for (int j = 0; j < 2; j++)
        bso[j] = (j * 16 + (lane >> 2)) * 384 + (((lane & 3) ^ swst) * 8);
    short* wsc = smem + 24576 + wid * 4096;  // wave scratch (8 KB)

    const short* sK = Wt + (size_t)(wid * 32) * 384;
    const short* sV = Wt + (size_t)(384 + wid * 32) * 384;
    const short* sQ = Wt + (size_t)(768 + wid * 32) * 384;
    const short* sP = WtP + (size_t)(wid * 32) * 384;

    // ---- phase 1: q prologue + gather skip + B1 ----
#pragma unroll
    for (int s = 0; s < 2; s++)
#pragma unroll
        for (int j = 0; j < 2; j++)
            glds16(sQ + bso[j] + s * 32, wsc + s * 1024 + j * 512);
    gatherA(xs);
    __syncthreads();  // B1

    // ---- phase 2: q-GEMM (swapped; 12 steps; vmcnt(2)) ----
    floatx4 aq[2][4];
#pragma unroll
    for (int a = 0; a < 2; a++)
#pragma unroll
        for (int b = 0; b < 4; b++)
#pragma unroll
            for (int r = 0; r < 4; r++) aq[a][b][r] = 0.f;
#pragma unroll
    for (int kt = 0; kt < 12; ++kt) {
        if (kt == 11) asm volatile("s_waitcnt vmcnt(0)" ::: "memory");
        else          asm volatile("s_waitcnt vmcnt(2)" ::: "memory");
        const int choff = ((kt * 4 + g4) ^ al7) * 8;
        short* hb = wsc + (kt & 1) * 1024;
        short8 af[4], bq[2];
#pragma unroll
        for (int b = 0; b < 4; b++)
            af[b] = *(const short8*)(smem + (b * 16 + l15) * 384 + choff);
#pragma unroll
        for (int a = 0; a < 2; a++)
            bq[a] = *(const short8*)(hb + (a * 16 + l15) * 32 + brd);
        __builtin_amdgcn_sched_barrier(0);
        asm volatile("s_waitcnt lgkmcnt(0)" ::: "memory");
        if (kt < 10) {
            int ko = (kt + 2) * 32;
#pragma unroll
            for (int j = 0; j < 2; j++) glds16(sQ + bso[j] + ko, hb + j * 512);
        }
        __builtin_amdgcn_sched_barrier(0);
#pragma unroll
        for (int a = 0; a < 2; a++)
#pragma unroll
            for (int b = 0; b < 4; b++)
                aq[a][b] = MFMA16(bq[a], af[b], aq[a][b]);
    }

    // ---- Q bounce: acc (d=a*16+g4*4+r, i=b*16+l15) -> Q[i][32d] @wsc+1024 ----
    const float scl = 0.17677669529663687f;
#pragma unroll
    for (int a = 0; a < 2; a++) {
        float4 bv = *(const float4*)(bskip + wid * 32 + a * 16 + g4 * 4);
#pragma unroll
        for (int b = 0; b < 4; b++) {
            uint2 pk;
            pk.x = cvt2bf(aq[a][b][0] + bv.x * scl, aq[a][b][1] + bv.y * scl);
            pk.y = cvt2bf(aq[a][b][2] + bv.z * scl, aq[a][b][3] + bv.w * scl);
            *(uint2*)(wsc + 1024 + (b * 16 + l15) * 32 + a * 16 + g4 * 4) = pk;
        }
    }
    short8 qf[4];
#pragma unroll
    for (int nj = 0; nj < 4; nj++)
        qf[nj] = *(const short8*)(wsc + 1024 + (nj * 16 + l15) * 32 + g4 * 8);
    lds_fence();  // qf reads must complete before kv-prologue glds overwrite

    // ---- kv prologue + B2 + gather query + B3 ----
#pragma unroll
    for (int s = 0; s < 2; s++)
#pragma unroll
        for (int j = 0; j < 2; j++) {
            glds16(sK + bso[j] + s * 32, wsc + s * 2048 + j * 512);
            glds16(sV + bso[j] + s * 32, wsc + s * 2048 + 1024 + j * 512);
        }
    __syncthreads();  // B2: all waves done reading A(skip)
    gatherA(xq);
    __syncthreads();  // B3

    // ---- dual k||v GEMM (12 steps; vmcnt(4)) ----
    floatx4 ak[2][4], av[2][4];
#pragma unroll
    for (int a = 0; a < 2; a++)
#pragma unroll
        for (int b = 0; b < 4; b++)
#pragma unroll
            for (int r = 0; r < 4; r++) { ak[a][b][r] = 0.f; av[a][b][r] = 0.f; }
#pragma unroll
    for (int kt = 0; kt < 12; ++kt) {
        if (kt == 11) asm volatile("s_waitcnt vmcnt(0)" ::: "memory");
        else          asm volatile("s_waitcnt vmcnt(4)" ::: "memory");
        const int choff = ((kt * 4 + g4) ^ al7) * 8;
        short* hb = wsc + (kt & 1) * 2048;
        short8 af[4], bk[2], bv2[2];
#pragma unroll
        for (int b = 0; b < 4; b++)
            af[b] = *(const short8*)(smem + (b * 16 + l15) * 384 + choff);
#pragma unroll
        for (int a = 0; a < 2; a++) {
            bk[a]  = *(const short8*)(hb + (a * 16 + l15) * 32 + brd);
            bv2[a] = *(const short8*)(hb + 1024 + (a * 16 + l15) * 32 + brd);
        }
        __builtin_amdgcn_sched_barrier(0);
        asm volatile("s_waitcnt lgkmcnt(0)" ::: "memory");
        if (kt < 10) {
            int ko = (kt + 2) * 32;
#pragma unroll
            for (int j = 0; j < 2; j++) {
                glds16(sK + bso[j] + ko, hb + j * 512);
                glds16(sV + bso[j] + ko, hb + 1024 + j * 512);
            }
        }
        __builtin_amdgcn_sched_barrier(0);
#pragma unroll
        for (int a = 0; a < 2; a++)
#pragma unroll
            for (int b = 0; b < 4; b++) {
                ak[a][b] = MFMA16(bk[a], af[b], ak[a][b]);
                av[a][b] = MFMA16(af[b], bv2[a], av[a][b]);
            }
    }
    __syncthreads();  // B4: all waves done reading A(query)

    // ---- K bounce: K[t][32d] @wsc+0 ----
#pragma unroll
    for (int a = 0; a < 2; a++) {
        float4 bv = *(const float4*)(bqkv + wid * 32 + a * 16 + g4 * 4);
#pragma unroll
        for (int b = 0; b < 4; b++) {
            uint2 pk;
            pk.x = cvt2bf(ak[a][b][0] + bv.x, ak[a][b][1] + bv.y);
            pk.y = cvt2bf(ak[a][b][2] + bv.z, ak[a][b][3] + bv.w);
            *(uint2*)(wsc + (b * 16 + l15) * 32 + a * 16 + g4 * 4) = pk;
        }
    }
    // ---- V bounce: V^T[d][64t] chunk-swizzled @wsc+2048 ----
#pragma unroll
    for (int a = 0; a < 2; a++) {
        float bvs = bqkv[384 + wid * 32 + a * 16 + l15];
#pragma unroll
        for (int b = 0; b < 4; b++) {
            uint2 pk;
            pk.x = cvt2bf(av[a][b][0] + bvs, av[a][b][1] + bvs);
            pk.y = cvt2bf(av[a][b][2] + bvs, av[a][b][3] + bvs);
            int tch = b * 2 + (g4 >> 1);
            *(uint2*)(wsc + 2048 + (a * 16 + l15) * 64 +
                      ((tch ^ (l15 & 7)) * 8) + (g4 & 1) * 4) = pk;
        }
    }
    short8 kf[4], vf[2][2];
#pragma unroll
    for (int mi = 0; mi < 4; mi++)
        kf[mi] = *(const short8*)(wsc + (mi * 16 + l15) * 32 + g4 * 8);
#pragma unroll
    for (int ma = 0; ma < 2; ma++)
#pragma unroll
        for (int ks = 0; ks < 2; ks++)
            vf[ma][ks] = *(const short8*)(wsc + 2048 + (ma * 16 + l15) * 64 +
                                          (((ks * 4 + g4) ^ (l15 & 7)) * 8));

    // ---- attention: S^T = mfma(K,Q) ----
    floatx4 st[4][4];
#pragma unroll
    for (int mi = 0; mi < 4; mi++)
#pragma unroll
        for (int nj = 0; nj < 4; nj++)
#pragma unroll
            for (int r = 0; r < 4; r++) st[mi][nj][r] = 0.f;
#pragma unroll
    for (int mi = 0; mi < 4; mi++)
#pragma unroll
        for (int nj = 0; nj < 4; nj++)
            st[mi][nj] = MFMA16(kf[mi], qf[nj], st[mi][nj]);

    const float* bb = bias64 + wid * 4096;
#pragma unroll
    for (int nj = 0; nj < 4; nj++) {
        int i = nj * 16 + l15;
#pragma unroll
        for (int mi = 0; mi < 4; mi++) {
            floatx4 b4 = *(const floatx4*)(bb + i * 64 + mi * 16 + g4 * 4);
            st[mi][nj] += b4;
        }
    }

    if (wy == 11 || wx == 11) {
        int wy11 = (wy == 11), wx11 = (wx == 11);
        int ri[4];
#pragma unroll
        for (int nj = 0; nj < 4; nj++) {
            int t = nj * 16 + l15;
            int hh = wy11 ? (((t >> 3) >= 4) ? 2 : 1) : 0;
            int ww = wx11 ? (((t & 7) >= 4) ? 2 : 1) : 0;
            ri[nj] = hh * 3 + ww;
        }
#pragma unroll
        for (int mi = 0; mi < 4; mi++)
#pragma unroll
            for (int r = 0; r < 4; r++) {
                int t = mi * 16 + g4 * 4 + r;
                int hh = wy11 ? (((t >> 3) >= 4) ? 2 : 1) : 0;
                int ww = wx11 ? (((t & 7) >= 4) ? 2 : 1) : 0;
                int rk = hh * 3 + ww;
#pragma unroll
                for (int nj = 0; nj < 4; nj++)
                    if (rk != ri[nj]) st[mi][nj][r] -= 100.0f;
            }
    }

    float rden[4];
#pragma unroll
    for (int nj = 0; nj < 4; nj++) {
        float m = -1e30f;
#pragma unroll
        for (int mi = 0; mi < 4; mi++)
#pragma unroll
            for (int r = 0; r < 4; r++) m = fmaxf(m, st[mi][nj][r]);
        m = fmaxf(m, __shfl_xor(m, 16));
        m = fmaxf(m, __shfl_xor(m, 32));
        float s = 0.f;
#pragma unroll
        for (int mi = 0; mi < 4; mi++)
#pragma unroll
            for (int r = 0; r < 4; r++) {
                float p = __expf(st[mi][nj][r] - m);
                st[mi][nj][r] = p;
                s += p;
            }
        s += __shfl_xor(s, 16);
        s += __shfl_xor(s, 32);
        rden[nj] = 1.0f / s;
    }

    // ---- P bounce: P[i][64kk] chunk-swizzled over full scratch ----
#pragma unroll
    for (int mi = 0; mi < 4; mi++)
#pragma unroll
        for (int nj = 0; nj < 4; nj++) {
            uint2 pk;
            pk.x = cvt2bf(st[mi][nj][0], st[mi][nj][1]);
            pk.y = cvt2bf(st[mi][nj][2], st[mi][nj][3]);
            int kch = mi * 2 + (g4 >> 1);
            *(uint2*)(wsc + (nj * 16 + l15) * 64 +
                      ((kch ^ (l15 & 7)) * 8) + (g4 & 1) * 4) = pk;
        }

    // ---- PV: out^T = mfma(V^T, P^T) ----
    floatx4 o[2][4];
#pragma unroll
    for (int ma = 0; ma < 2; ma++)
#pragma unroll
        for (int nj = 0; nj < 4; nj++)
#pragma unroll
            for (int r = 0; r < 4; r++) o[ma][nj][r] = 0.f;
#pragma unroll
    for (int ks = 0; ks < 2; ks++) {
        short8 pb[4];
#pragma unroll
        for (int nj = 0; nj < 4; nj++)
            pb[nj] = *(const short8*)(wsc + (nj * 16 + l15) * 64 +
                                      (((ks * 4 + g4) ^ (l15 & 7)) * 8));
#pragma unroll
        for (int ma = 0; ma < 2; ma++)
#pragma unroll
            for (int nj = 0; nj < 4; nj++)
                o[ma][nj] = MFMA16(vf[ma][ks], pb[nj], o[ma][nj]);
    }
    lds_fence();  // pb reads must complete before proj-prologue glds overwrite

    // ---- proj prologue (scratch reusable after pb reads) ----
#pragma unroll
    for (int s = 0; s < 2; s++)
#pragma unroll
        for (int j = 0; j < 2; j++)
            glds16(sP + bso[j] + s * 32, wsc + s * 1024 + j * 512);

    // ---- out -> A-region (chunk-swizzled [t][384]) ----
#pragma unroll
    for (int ma = 0; ma < 2; ma++)
#pragma unroll
        for (int nj = 0; nj < 4; nj++) {
            int i = nj * 16 + l15;
            uint2 pk;
            pk.x = cvt2bf(o[ma][nj][0] * rden[nj], o[ma][nj][1] * rden[nj]);
            pk.y = cvt2bf(o[ma][nj][2] * rden[nj], o[ma][nj][3] * rden[nj]);
            int ch = wid * 4 + ma * 2 + (g4 >> 1);
            *(uint2*)(smem + i * 384 + ((ch ^ (i & 7)) * 8) + (g4 & 1) * 4) = pk;
        }
    __syncthreads();  // B5

    // ---- proj GEMM (swapped; 12 steps; vmcnt(2)) ----
    floatx4 ap[2][4];
#pragma unroll
    for (int a = 0; a < 2; a++)
#pragma unroll
        for (int b = 0; b < 4; b++)
#pragma unroll
            for (int r = 0; r < 4; r++) ap[a][b][r] = 0.f;
#pragma unroll
    for (int kt = 0; kt < 12; ++kt) {
        if (kt == 11) asm volatile("s_waitcnt vmcnt(0)" ::: "memory");
        else          asm volatile("s_waitcnt vmcnt(2)" ::: "memory");
        const int choff = ((kt * 4 + g4) ^ al7) * 8;
        short* hb = wsc + (kt & 1) * 1024;
        short8 af[4], bp[2];
#pragma unroll
        for (int b = 0; b < 4; b++)
            af[b] = *(const short8*)(smem + (b * 16 + l15) * 384 + choff);
#pragma unroll
        for (int a = 0; a < 2; a++)
            bp[a] = *(const short8*)(hb + (a * 16 + l15) * 32 + brd);
        __builtin_amdgcn_sched_barrier(0);
        asm volatile("s_waitcnt lgkmcnt(0)" ::: "memory");
        if (kt < 10) {
            int ko = (kt + 2) * 32;
#pragma unroll
            for (int j = 0; j < 2; j++) glds16(sP + bso[j] + ko, hb + j * 512);
        }
        __builtin_amdgcn_sched_barrier(0);
#pragma unroll
        for (int a = 0; a < 2; a++)
#pragma unroll
            for (int b = 0; b < 4; b++)
                ap[a][b] = MFMA16(bp[a], af[b], ap[a][b]);
    }

    // ---- epilogue: + bias, inverse shift scatter, float4 ----
#pragma unroll
    for (int a = 0; a < 2; a++) {
        int n = wid * 32 + a * 16 + g4 * 4;
        float4 bv = *(const float4*)(bproj + n);
#pragma unroll
        for (int b = 0; b < 4; b++) {
            int t = b * 16 + l15;
            int yy = wy * 8 + (t >> 3) + 4; if (yy >= 96) yy -= 96;
            int xx = wx * 8 + (t & 7) + 4;  if (xx >= 96) xx -= 96;
            floatx4 ov = ap[a][b];
            ov[0] += bv.x; ov[1] += bv.y; ov[2] += bv.z; ov[3] += bv.w;
            *(floatx4*)(&out[((size_t)b_img * 9216 + yy * 96 + xx) * 384 + n]) = ov;
        }
    }
}

// ---------------- launcher ----------------
extern "C" void kernel_launch(void* const* d_in, const int* in_sizes, int n_in,
                              void* d_out, int out_size, void* d_ws, size_t ws_size,
                              hipStream_t stream) {
    const float* query = (const float*)d_in[0];
    const float* skipq = (const float*)d_in[1];
    const float* Wqkv  = (const float*)d_in[2];
    const float* bqkv  = (const float*)d_in[3];
    const float* Wskip = (const float*)d_in[4];
    const float* bskip = (const float*)d_in[5];
    const float* rpb   = (const float*)d_in[6];
    const float* Wproj = (const float*)d_in[7];
    const float* bproj = (const float*)d_in[8];
    float* out = (float*)d_out;

    int M = in_sizes[0] / 384;   // total tokens = 147456 for B=16
    int nwin = M / 64;           // 2304

    char* ws = (char*)d_ws;
    size_t off = 0;
    auto alloc = [&](size_t bytes) -> void* {
        void* p = ws + off;
        off = (off + bytes + 255) & ~(size_t)255;
        return p;
    };
    short* Wt     = (short*)alloc((size_t)1152 * 384 * 2);
    short* WtP    = (short*)alloc((size_t)384 * 384 * 2);
    float* bias64 = (float*)alloc((size_t)12 * 64 * 64 * 4);
    (void)ws_size;

    hipLaunchKernelGGL(prep_wt, dim3(216), dim3(256), 0, stream, Wqkv, Wskip, Wt);
    hipLaunchKernelGGL(prep_wtp, dim3(72), dim3(256), 0, stream, Wproj, WtP);
    hipLaunchKernelGGL(prep_bias, dim3(192), dim3(256), 0, stream, rpb, bias64);
    hipLaunchKernelGGL(fused_win, dim3(nwin), dim3(768), 0, stream,
                       query, skipq, Wt, WtP, bqkv, bskip, bproj, bias64, out);
}

// Round 16
// 464.721 us; speedup vs baseline: 1.1972x; 1.0726x over previous
//
#include <hip/hip_runtime.h>
#include <hip/hip_bf16.h>

// ShiftWindowMSA fully-fused kernel for MI355X (gfx950).
// R16 = R15 + (1) fp32 output bounced through wave scratch -> full-128B-line
// stores, (2) early xq register gather overlapped with q-GEMM (separate
// gather phase deleted), (3) chunk-XOR swizzle on Q/K bounces (8-way -> 2-way
// LDS conflicts). Block = 1 window (768 thr, 12 waves, wave = head).

typedef __attribute__((ext_vector_type(8))) short short8;
typedef __attribute__((ext_vector_type(4))) float floatx4;

#define MFMA16(a, b, c) __builtin_amdgcn_mfma_f32_16x16x32_bf16(a, b, c, 0, 0, 0)

__device__ __forceinline__ short f2bf(float f) {
    __hip_bfloat16 h = __float2bfloat16(f);
    return *reinterpret_cast<short*>(&h);
}

// packed fp32->bf16 RNE
__device__ __forceinline__ unsigned cvt2bf(float lo, float hi) {
    unsigned r;
    asm("v_cvt_pk_bf16_f32 %0, %1, %2" : "=v"(r) : "v"(lo), "v"(hi));
    return r;
}

__device__ __forceinline__ void glds16(const void* g, void* l) {
    __builtin_amdgcn_global_load_lds(
        (const __attribute__((address_space(1))) void*)g,
        (__attribute__((address_space(3))) void*)l, 16, 0, 0);
}

__device__ __forceinline__ void lds_fence() {
    asm volatile("s_waitcnt lgkmcnt(0)" ::: "memory");
    __builtin_amdgcn_sched_barrier(0);
}

// ---------------- prep kernels ----------------

__global__ __launch_bounds__(256) void prep_wt(const float* __restrict__ Wqkv,
                                               const float* __restrict__ Wskip,
                                               short* __restrict__ Wt) {
    int tid = blockIdx.x * 256 + threadIdx.x;  // 384*144 = 55296
    if (tid >= 384 * 144) return;
    int k = tid / 144;
    int n8 = (tid % 144) * 8;
#pragma unroll
    for (int e = 0; e < 8; e++) {
        int n = n8 + e;
        float v = (n < 768) ? Wqkv[k * 768 + n]
                            : Wskip[k * 384 + (n - 768)] * 0.17677669529663687f;
        Wt[(size_t)n * 384 + k] = f2bf(v);
    }
}

__global__ __launch_bounds__(256) void prep_wtp(const float* __restrict__ Wproj,
                                                short* __restrict__ WtP) {
    int tid = blockIdx.x * 256 + threadIdx.x;  // 384*48 = 18432
    if (tid >= 384 * 48) return;
    int k = tid / 48;
    int n8 = (tid % 48) * 8;
#pragma unroll
    for (int e = 0; e < 8; e++) {
        int n = n8 + e;
        WtP[(size_t)n * 384 + k] = f2bf(Wproj[k * 384 + n]);
    }
}

__global__ __launch_bounds__(256) void prep_bias(const float* __restrict__ rpb,
                                                 float* __restrict__ bias64) {
    int tid = blockIdx.x * 256 + threadIdx.x;  // 12*64*64 = 49152
    if (tid >= 49152) return;
    int h = tid >> 12;
    int rem = tid & 4095;
    int i = rem >> 6, kk = rem & 63;
    int j = 63 - kk;
    int ridx = 15 * (i >> 3) + (i & 7) + 15 * (j >> 3) + (j & 7);
    bias64[tid] = rpb[ridx * 12 + h];
}

// ---------------- fused per-window kernel ----------------
__global__ __launch_bounds__(768, 1) void fused_win(
    const float* __restrict__ xq, const float* __restrict__ xs,
    const short* __restrict__ Wt, const short* __restrict__ WtP,
    const float* __restrict__ bqkv, const float* __restrict__ bskip,
    const float* __restrict__ bproj, const float* __restrict__ bias64,
    float* __restrict__ out) {
    __shared__ short smem[73728];  // A/out [0,24576); wave scratch @24576+wid*4096

    const int win = blockIdx.x;
    const int tid = threadIdx.x, lane = tid & 63, wid = tid >> 6;  // wid = head
    const int l15 = lane & 15, g4 = lane >> 4;
    const int al7 = l15 & 7;
    const int brd = (g4 ^ ((l15 ^ (l15 >> 2)) & 3)) * 8;

    const int b_img = win / 144, wr = win % 144;
    const int wy = wr / 12, wx = wr % 12;

    // gather mapping: 64 rows x 12 threads (32 cols each)
    const int gr = tid / 12, gj = tid - gr * 12;
    int gyy = wy * 8 + (gr >> 3) + 4; if (gyy >= 96) gyy -= 96;
    int gxx = wx * 8 + (gr & 7) + 4;  if (gxx >= 96) gxx -= 96;
    const size_t grow = ((size_t)b_img * 9216 + gyy * 96 + gxx) * 384;
    short* lrow = smem + gr * 384;
    const int gr7 = gr & 7;

    auto gatherA = [&](const float* src) {
        const float* rb = src + grow;
#pragma unroll
        for (int cc = 0; cc < 4; cc++) {
            int c = gj * 4 + cc;
            float4 f0 = *(const float4*)(rb + c * 8);
            float4 f1 = *(const float4*)(rb + c * 8 + 4);
            uint4 u;
            u.x = cvt2bf(f0.x, f0.y); u.y = cvt2bf(f0.z, f0.w);
            u.z = cvt2bf(f1.x, f1.y); u.w = cvt2bf(f1.z, f1.w);
            *(uint4*)(lrow + ((c ^ gr7) * 8)) = u;
        }
    };

    // B strip staging (32 rows x 32 k per step = 2 glds of 1 KB)
    const int swst = ((lane >> 2) ^ (lane >> 4)) & 3;
    int bso[2];
#pragma unroll
    for (int j = 0; j < 2; j++)
        bso[j] = (j * 16 + (lane >> 2)) * 384 + (((lane & 3) ^ swst) * 8);
    short* wsc = smem + 24576 + wid * 4096;  // wave scratch (8 KB)

    const short* sK = Wt + (size_t)(wid * 32) * 384;
    const short* sV = Wt + (size_t)(384 + wid * 32) * 384;
    const short* sQ = Wt + (size_t)(768 + wid * 32) * 384;
    const short* sP = WtP + (size_t)(wid * 32) * 384;

    // ---- phase 1: q prologue + gather skip + early xq reg-gather + B1 ----
#pragma unroll
    for (int s = 0; s < 2; s++)
#pragma unroll
        for (int j = 0; j < 2; j++)
            glds16(sQ + bso[j] + s * 32, wsc + s * 1024 + j * 512);
    gatherA(xs);
    float4 xr[8];  // xq rows in flight during q-GEMM (T14 split)
    {
        const float* rb = xq + grow;
#pragma unroll
        for (int cc = 0; cc < 4; cc++) {
            xr[cc * 2]     = *(const float4*)(rb + (gj * 4 + cc) * 8);
            xr[cc * 2 + 1] = *(const float4*)(rb + (gj * 4 + cc) * 8 + 4);
        }
    }
    __syncthreads();  // B1

    // ---- phase 2: q-GEMM (swapped; 12 steps; vmcnt(2)) ----
    floatx4 aq[2][4];
#pragma unroll
    for (int a = 0; a < 2; a++)
#pragma unroll
        for (int b = 0; b < 4; b++)
#pragma unroll
            for (int r = 0; r < 4; r++) aq[a][b][r] = 0.f;
#pragma unroll
    for (int kt = 0; kt < 12; ++kt) {
        if (kt == 11) asm volatile("s_waitcnt vmcnt(0)" ::: "memory");
        else          asm volatile("s_waitcnt vmcnt(2)" ::: "memory");
        const int choff = ((kt * 4 + g4) ^ al7) * 8;
        short* hb = wsc + (kt & 1) * 1024;
        short8 af[4], bq[2];
#pragma unroll
        for (int b = 0; b < 4; b++)
            af[b] = *(const short8*)(smem + (b * 16 + l15) * 384 + choff);
#pragma unroll
        for (int a = 0; a < 2; a++)
            bq[a] = *(const short8*)(hb + (a * 16 + l15) * 32 + brd);
        __builtin_amdgcn_sched_barrier(0);
        asm volatile("s_waitcnt lgkmcnt(0)" ::: "memory");
        if (kt < 10) {
            int ko = (kt + 2) * 32;
#pragma unroll
            for (int j = 0; j < 2; j++) glds16(sQ + bso[j] + ko, hb + j * 512);
        }
        __builtin_amdgcn_sched_barrier(0);
#pragma unroll
        for (int a = 0; a < 2; a++)
#pragma unroll
            for (int b = 0; b < 4; b++)
                aq[a][b] = MFMA16(bq[a], af[b], aq[a][b]);
    }

    // ---- Q bounce (chunk-XOR swizzled): Q[i][32d] @wsc+1024 ----
    const float scl = 0.17677669529663687f;
#pragma unroll
    for (int a = 0; a < 2; a++) {
        float4 bv = *(const float4*)(bskip + wid * 32 + a * 16 + g4 * 4);
#pragma unroll
        for (int b = 0; b < 4; b++) {
            uint2 pk;
            pk.x = cvt2bf(aq[a][b][0] + bv.x * scl, aq[a][b][1] + bv.y * scl);
            pk.y = cvt2bf(aq[a][b][2] + bv.z * scl, aq[a][b][3] + bv.w * scl);
            int row = b * 16 + l15;
            int phys = (a * 2 + (g4 >> 1)) ^ (row & 3);
            *(uint2*)(wsc + 1024 + row * 32 + phys * 8 + (g4 & 1) * 4) = pk;
        }
    }
    short8 qf[4];
#pragma unroll
    for (int nj = 0; nj < 4; nj++) {
        int row = nj * 16 + l15;
        qf[nj] = *(const short8*)(wsc + 1024 + row * 32 + ((g4 ^ (row & 3)) * 8));
    }
    lds_fence();  // qf reads must complete before kv-prologue glds overwrite

    // ---- kv prologue + B2 + xq regs -> A + B3 ----
#pragma unroll
    for (int s = 0; s < 2; s++)
#pragma unroll
        for (int j = 0; j < 2; j++) {
            glds16(sK + bso[j] + s * 32, wsc + s * 2048 + j * 512);
            glds16(sV + bso[j] + s * 32, wsc + s * 2048 + 1024 + j * 512);
        }
    __syncthreads();  // B2: all waves done reading A(skip)
#pragma unroll
    for (int cc = 0; cc < 4; cc++) {
        int c = gj * 4 + cc;
        uint4 u;
        u.x = cvt2bf(xr[cc * 2].x, xr[cc * 2].y);
        u.y = cvt2bf(xr[cc * 2].z, xr[cc * 2].w);
        u.z = cvt2bf(xr[cc * 2 + 1].x, xr[cc * 2 + 1].y);
        u.w = cvt2bf(xr[cc * 2 + 1].z, xr[cc * 2 + 1].w);
        *(uint4*)(lrow + ((c ^ gr7) * 8)) = u;
    }
    __syncthreads();  // B3

    // ---- dual k||v GEMM (12 steps; vmcnt(4)) ----
    floatx4 ak[2][4], av[2][4];
#pragma unroll
    for (int a = 0; a < 2; a++)
#pragma unroll
        for (int b = 0; b < 4; b++)
#pragma unroll
            for (int r = 0; r < 4; r++) { ak[a][b][r] = 0.f; av[a][b][r] = 0.f; }
#pragma unroll
    for (int kt = 0; kt < 12; ++kt) {
        if (kt == 11) asm volatile("s_waitcnt vmcnt(0)" ::: "memory");
        else          asm volatile("s_waitcnt vmcnt(4)" ::: "memory");
        const int choff = ((kt * 4 + g4) ^ al7) * 8;
        short* hb = wsc + (kt & 1) * 2048;
        short8 af[4], bk[2], bv2[2];
#pragma unroll
        for (int b = 0; b < 4; b++)
            af[b] = *(const short8*)(smem + (b * 16 + l15) * 384 + choff);
#pragma unroll
        for (int a = 0; a < 2; a++) {
            bk[a]  = *(const short8*)(hb + (a * 16 + l15) * 32 + brd);
            bv2[a] = *(const short8*)(hb + 1024 + (a * 16 + l15) * 32 + brd);
        }
        __builtin_amdgcn_sched_barrier(0);
        asm volatile("s_waitcnt lgkmcnt(0)" ::: "memory");
        if (kt < 10) {
            int ko = (kt + 2) * 32;
#pragma unroll
            for (int j = 0; j < 2; j++) {
                glds16(sK + bso[j] + ko, hb + j * 512);
                glds16(sV + bso[j] + ko, hb + 1024 + j * 512);
            }
        }
        __builtin_amdgcn_sched_barrier(0);
#pragma unroll
        for (int a = 0; a < 2; a++)
#pragma unroll
            for (int b = 0; b < 4; b++) {
                ak[a][b] = MFMA16(bk[a], af[b], ak[a][b]);
                av[a][b] = MFMA16(af[b], bv2[a], av[a][b]);
            }
    }
    __syncthreads();  // B4: all waves done reading A(query)

    // ---- K bounce (chunk-XOR swizzled): K[t][32d] @wsc+0 ----
#pragma unroll
    for (int a = 0; a < 2; a++) {
        float4 bv = *(const float4*)(bqkv + wid * 32 + a * 16 + g4 * 4);
#pragma unroll
        for (int b = 0; b < 4; b++) {
            uint2 pk;
            pk.x = cvt2bf(ak[a][b][0] + bv.x, ak[a][b][1] + bv.y);
            pk.y = cvt2bf(ak[a][b][2] + bv.z, ak[a][b][3] + bv.w);
            int row = b * 16 + l15;
            int phys = (a * 2 + (g4 >> 1)) ^ (row & 3);
            *(uint2*)(wsc + row * 32 + phys * 8 + (g4 & 1) * 4) = pk;
        }
    }
    // ---- V bounce: V^T[d][64t] chunk-swizzled @wsc+2048 ----
#pragma unroll
    for (int a = 0; a < 2; a++) {
        float bvs = bqkv[384 + wid * 32 + a * 16 + l15];
#pragma unroll
        for (int b = 0; b < 4; b++) {
            uint2 pk;
            pk.x = cvt2bf(av[a][b][0] + bvs, av[a][b][1] + bvs);
            pk.y = cvt2bf(av[a][b][2] + bvs, av[a][b][3] + bvs);
            int tch = b * 2 + (g4 >> 1);
            *(uint2*)(wsc + 2048 + (a * 16 + l15) * 64 +
                      ((tch ^ (l15 & 7)) * 8) + (g4 & 1) * 4) = pk;
        }
    }
    short8 kf[4], vf[2][2];
#pragma unroll
    for (int mi = 0; mi < 4; mi++) {
        int row = mi * 16 + l15;
        kf[mi] = *(const short8*)(wsc + row * 32 + ((g4 ^ (row & 3)) * 8));
    }
#pragma unroll
    for (int ma = 0; ma < 2; ma++)
#pragma unroll
        for (int ks = 0; ks < 2; ks++)
            vf[ma][ks] = *(const short8*)(wsc + 2048 + (ma * 16 + l15) * 64 +
                                          (((ks * 4 + g4) ^ (l15 & 7)) * 8));

    // ---- attention: S^T = mfma(K,Q) ----
    floatx4 st[4][4];
#pragma unroll
    for (int mi = 0; mi < 4; mi++)
#pragma unroll
        for (int nj = 0; nj < 4; nj++)
#pragma unroll
            for (int r = 0; r < 4; r++) st[mi][nj][r] = 0.f;
#pragma unroll
    for (int mi = 0; mi < 4; mi++)
#pragma unroll
        for (int nj = 0; nj < 4; nj++)
            st[mi][nj] = MFMA16(kf[mi], qf[nj], st[mi][nj]);

    const float* bb = bias64 + wid * 4096;
#pragma unroll
    for (int nj = 0; nj < 4; nj++) {
        int i = nj * 16 + l15;
#pragma unroll
        for (int mi = 0; mi < 4; mi++) {
            floatx4 b4 = *(const floatx4*)(bb + i * 64 + mi * 16 + g4 * 4);
            st[mi][nj] += b4;
        }
    }

    if (wy == 11 || wx == 11) {
        int wy11 = (wy == 11), wx11 = (wx == 11);
        int ri[4];
#pragma unroll
        for (int nj = 0; nj < 4; nj++) {
            int t = nj * 16 + l15;
            int hh = wy11 ? (((t >> 3) >= 4) ? 2 : 1) : 0;
            int ww = wx11 ? (((t & 7) >= 4) ? 2 : 1) : 0;
            ri[nj] = hh * 3 + ww;
        }
#pragma unroll
        for (int mi = 0; mi < 4; mi++)
#pragma unroll
            for (int r = 0; r < 4; r++) {
                int t = mi * 16 + g4 * 4 + r;
                int hh = wy11 ? (((t >> 3) >= 4) ? 2 : 1) : 0;
                int ww = wx11 ? (((t & 7) >= 4) ? 2 : 1) : 0;
                int rk = hh * 3 + ww;
#pragma unroll
                for (int nj = 0; nj < 4; nj++)
                    if (rk != ri[nj]) st[mi][nj][r] -= 100.0f;
            }
    }

    float rden[4];
#pragma unroll
    for (int nj = 0; nj < 4; nj++) {
        float m = -1e30f;
#pragma unroll
        for (int mi = 0; mi < 4; mi++)
#pragma unroll
            for (int r = 0; r < 4; r++) m = fmaxf(m, st[mi][nj][r]);
        m = fmaxf(m, __shfl_xor(m, 16));
        m = fmaxf(m, __shfl_xor(m, 32));
        float s = 0.f;
#pragma unroll
        for (int mi = 0; mi < 4; mi++)
#pragma unroll
            for (int r = 0; r < 4; r++) {
                float p = __expf(st[mi][nj][r] - m);
                st[mi][nj][r] = p;
                s += p;
            }
        s += __shfl_xor(s, 16);
        s += __shfl_xor(s, 32);
        rden[nj] = 1.0f / s;
    }

    // ---- P bounce: P[i][64kk] chunk-swizzled over full scratch ----
#pragma unroll
    for (int mi = 0; mi < 4; mi++)
#pragma unroll
        for (int nj = 0; nj < 4; nj++) {
            uint2 pk;
            pk.x = cvt2bf(st[mi][nj][0], st[mi][nj][1]);
            pk.y = cvt2bf(st[mi][nj][2], st[mi][nj][3]);
            int kch = mi * 2 + (g4 >> 1);
            *(uint2*)(wsc + (nj * 16 + l15) * 64 +
                      ((kch ^ (l15 & 7)) * 8) + (g4 & 1) * 4) = pk;
        }

    // ---- PV: out^T = mfma(V^T, P^T) ----
    floatx4 o[2][4];
#pragma unroll
    for (int ma = 0; ma < 2; ma++)
#pragma unroll
        for (int nj = 0; nj < 4; nj++)
#pragma unroll
            for (int r = 0; r < 4; r++) o[ma][nj][r] = 0.f;
#pragma unroll
    for (int ks = 0; ks < 2; ks++) {
        short8 pb[4];
#pragma unroll
        for (int nj = 0; nj < 4; nj++)
            pb[nj] = *(const short8*)(wsc + (nj * 16 + l15) * 64 +
                                      (((ks * 4 + g4) ^ (l15 & 7)) * 8));
#pragma unroll
        for (int ma = 0; ma < 2; ma++)
#pragma unroll
            for (int nj = 0; nj < 4; nj++)
                o[ma][nj] = MFMA16(vf[ma][ks], pb[nj], o[ma][nj]);
    }
    lds_fence();  // pb reads must complete before proj-prologue glds overwrite

    // ---- proj prologue (scratch reusable after pb reads) ----
#pragma unroll
    for (int s = 0; s < 2; s++)
#pragma unroll
        for (int j = 0; j < 2; j++)
            glds16(sP + bso[j] + s * 32, wsc + s * 1024 + j * 512);

    // ---- out -> A-region (chunk-swizzled [t][384]) ----
#pragma unroll
    for (int ma = 0; ma < 2; ma++)
#pragma unroll
        for (int nj = 0; nj < 4; nj++) {
            int i = nj * 16 + l15;
            uint2 pk;
            pk.x = cvt2bf(o[ma][nj][0] * rden[nj], o[ma][nj][1] * rden[nj]);
            pk.y = cvt2bf(o[ma][nj][2] * rden[nj], o[ma][nj][3] * rden[nj]);
            int ch = wid * 4 + ma * 2 + (g4 >> 1);
            *(uint2*)(smem + i * 384 + ((ch ^ (i & 7)) * 8) + (g4 & 1) * 4) = pk;
        }
    __syncthreads();  // B5

    // ---- proj GEMM (swapped; 12 steps; vmcnt(2)) ----
    floatx4 ap[2][4];
#pragma unroll
    for (int a = 0; a < 2; a++)
#pragma unroll
        for (int b = 0; b < 4; b++)
#pragma unroll
            for (int r = 0; r < 4; r++) ap[a][b][r] = 0.f;
#pragma unroll
    for (int kt = 0; kt < 12; ++kt) {
        if (kt == 11) asm volatile("s_waitcnt vmcnt(0)" ::: "memory");
        else          asm volatile("s_waitcnt vmcnt(2)" ::: "memory");
        const int choff = ((kt * 4 + g4) ^ al7) * 8;
        short* hb = wsc + (kt & 1) * 1024;
        short8 af[4], bp[2];
#pragma unroll
        for (int b = 0; b < 4; b++)
            af[b] = *(const short8*)(smem + (b * 16 + l15) * 384 + choff);
#pragma unroll
        for (int a = 0; a < 2; a++)
            bp[a] = *(const short8*)(hb + (a * 16 + l15) * 32 + brd);
        __builtin_amdgcn_sched_barrier(0);
        asm volatile("s_waitcnt lgkmcnt(0)" ::: "memory");
        if (kt < 10) {
            int ko = (kt + 2) * 32;
#pragma unroll
            for (int j = 0; j < 2; j++) glds16(sP + bso[j] + ko, hb + j * 512);
        }
        __builtin_amdgcn_sched_barrier(0);
#pragma unroll
        for (int a = 0; a < 2; a++)
#pragma unroll
            for (int b = 0; b < 4; b++)
                ap[a][b] = MFMA16(bp[a], af[b], ap[a][b]);
    }

    // ---- epilogue: fp32 bounce through wave scratch -> full-line stores ----
    float* fsc = (float*)wsc;  // [64][32] fp32, chunk-XOR swizzled
#pragma unroll
    for (int a = 0; a < 2; a++) {
        float4 bv = *(const float4*)(bproj + wid * 32 + a * 16 + g4 * 4);
#pragma unroll
        for (int b = 0; b < 4; b++) {
            int row = b * 16 + l15;
            int phys = (a * 4 + g4) ^ (row & 7);
            floatx4 ov = ap[a][b];
            ov[0] += bv.x; ov[1] += bv.y; ov[2] += bv.z; ov[3] += bv.w;
            *(floatx4*)(fsc + row * 32 + phys * 4) = ov;
        }
    }
    lds_fence();
    {
        const int r8 = lane >> 3, c8 = lane & 7;
#pragma unroll
        for (int it = 0; it < 8; it++) {
            int row = it * 8 + r8;
            floatx4 ov = *(const floatx4*)(fsc + row * 32 + ((c8 ^ r8) * 4));
            int yy = wy * 8 + (row >> 3) + 4; if (yy >= 96) yy -= 96;
            int xx = wx * 8 + (row & 7) + 4;  if (xx >= 96) xx -= 96;
            *(floatx4*)(&out[((size_t)b_img * 9216 + yy * 96 + xx) * 384 +
                             wid * 32 + c8 * 4]) = ov;
        }
    }
}

// ---------------- launcher ----------------
extern "C" void kernel_launch(void* const* d_in, const int* in_sizes, int n_in,
                              void* d_out, int out_size, void* d_ws, size_t ws_size,
                              hipStream_t stream) {
    const float* query = (const float*)d_in[0];
    const float* skipq = (const float*)d_in[1];
    const float* Wqkv  = (const float*)d_in[2];
    const float* bqkv  = (const float*)d_in[3];
    const float* Wskip = (const float*)d_in[4];
    const float* bskip = (const float*)d_in[5];
    const float* rpb   = (const float*)d_in[6];
    const float* Wproj = (const float*)d_in[7];
    const float* bproj = (const float*)d_in[8];
    float* out = (float*)d_out;

    int M = in_sizes[0] / 384;   // total tokens = 147456 for B=16
    int nwin = M / 64;           // 2304

    char* ws = (char*)d_ws;
    size_t off = 0;
    auto alloc = [&](size_t bytes) -> void* {
        void* p = ws + off;
        off = (off + bytes + 255) & ~(size_t)255;
        return p;
    };
    short* Wt     = (short*)alloc((size_t)1152 * 384 * 2);
    short* WtP    = (short*)alloc((size_t)384 * 384 * 2);
    float* bias64 = (float*)alloc((size_t)12 * 64 * 64 * 4);
    (void)ws_size;

    hipLaunchKernelGGL(prep_wt, dim3(216), dim3(256), 0, stream, Wqkv, Wskip, Wt);
    hipLaunchKernelGGL(prep_wtp, dim3(72), dim3(256), 0, stream, Wproj, WtP);
    hipLaunchKernelGGL(prep_bias, dim3(192), dim3(256), 0, stream, rpb, bias64);
    hipLaunchKernelGGL(fused_win, dim3(nwin), dim3(768), 0, stream,
                       query, skipq, Wt, WtP, bqkv, bskip, bproj, bias64, out);
}